// Round 7
// baseline (112.569 us; speedup 1.0000x reference)
//
#include <hip/hip_runtime.h>
#include <stdint.h>

#define SHAPE    512
#define DEPTH    9
#define NCELLS   (SHAPE * SHAPE)
#define NB       8                 // batches
#define RANGES   1024              // cell ranges per batch
#define CR       (NCELLS / RANGES) // 256 cells per range
#define CRSHIFT  8
#define CAP      512               // bucket capacity (mean 195, sigma ~14 -> ~22 sigma)
#define CAPSHIFT 9
#define NCHUNK   32                // point chunks per batch (counting-sort granularity)
#define SENT     0xFFFFFFFFu

typedef float f32x4 __attribute__((ext_vector_type(4)));   // native vector for nontemporal store

// ---- fast path: counting-sort binning + LDS cascade group ----

// Pass A: per (chunk, batch) histogram over the cell-ranges. 512 threads:
// 8 waves/CU (grid is 1 block/CU) to hide load+LDS-atomic latency.
__global__ __launch_bounds__(512) void hist_kernel(const float4* __restrict__ pts,
                                                   unsigned* __restrict__ hist,
                                                   int nPerB, int chSz) {
    __shared__ unsigned lh[RANGES];
    int c = blockIdx.x, b = blockIdx.y;
    for (int r = threadIdx.x; r < RANGES; r += 512) lh[r] = 0;
    __syncthreads();

    int i0 = c * chSz;
    int i1 = i0 + chSz; if (i1 > nPerB) i1 = nPerB;
    const float4* pb = pts + (size_t)b * nPerB;
    for (int i = i0 + threadIdx.x; i < i1; i += 512) {
        float4 p = pb[i];
        if (p.x == 0.f && p.y == 0.f && p.z == 0.f && p.w == 0.f) continue;
        int xi = (int)(p.x * (float)SHAPE);   // trunc == reference astype(int32)
        int yi = (int)(p.y * (float)SHAPE);
        unsigned cell = (unsigned)(xi * SHAPE + yi);
        if (cell >= (unsigned)NCELLS) continue;
        atomicAdd(&lh[cell >> CRSHIFT], 1u);
    }
    __syncthreads();
    for (int r = threadIdx.x; r < RANGES; r += 512)
        hist[((size_t)(b * RANGES + r)) * NCHUNK + c] = lh[r];
}

// Pass B: one thread per (batch, range): prefix over chunks -> exact segment
// start positions; also emits the bucket total (no zero-init pass needed).
__global__ void prefix_kernel(const unsigned* __restrict__ hist,
                              unsigned* __restrict__ offs,
                              unsigned* __restrict__ cnt) {
    int tid = blockIdx.x * blockDim.x + threadIdx.x;   // (b*RANGES + r)
    if (tid >= NB * RANGES) return;
    size_t base = (size_t)tid * NCHUNK;
    unsigned run = (unsigned)tid << CAPSHIFT;          // bucket base position
    for (int c = 0; c < NCHUNK; ++c) {
        offs[base + c] = run;
        run += hist[base + c];
    }
    cnt[tid] = run - ((unsigned)tid << CAPSHIFT);      // total points in bucket
}

// Pass C: scatter points + indices into their exact bucket segments.
// Per-(chunk,range) streams are contiguous; bucket arrays are L3-resident
// (32 MB touched << 256 MB), so partial-line cost lands on L3, not HBM.
__global__ __launch_bounds__(512) void scatter_kernel(const float4* __restrict__ pts,
                                                      const unsigned* __restrict__ offs,
                                                      float4* __restrict__ bktP,
                                                      unsigned* __restrict__ bktI,
                                                      int nPerB, int chSz) {
    __shared__ unsigned cur[RANGES];
    int c = blockIdx.x, b = blockIdx.y;
    for (int r = threadIdx.x; r < RANGES; r += 512)
        cur[r] = offs[((size_t)(b * RANGES + r)) * NCHUNK + c];
    __syncthreads();

    int i0 = c * chSz;
    int i1 = i0 + chSz; if (i1 > nPerB) i1 = nPerB;
    const float4* pb = pts + (size_t)b * nPerB;
    for (int i = i0 + threadIdx.x; i < i1; i += 512) {
        float4 p = pb[i];
        if (p.x == 0.f && p.y == 0.f && p.z == 0.f && p.w == 0.f) continue;
        int xi = (int)(p.x * (float)SHAPE);
        int yi = (int)(p.y * (float)SHAPE);
        unsigned cell = (unsigned)(xi * SHAPE + yi);
        if (cell >= (unsigned)NCELLS) continue;
        unsigned r = cell >> CRSHIFT;
        unsigned pos = atomicAdd(&cur[r], 1u);
        unsigned end = ((unsigned)(b * RANGES + r) + 1u) << CAPSHIFT;
        if (pos < end) {                               // overflow points dropped
            bktP[pos] = p;
            bktI[pos] = (unsigned)i;
        }
    }
}

// Phase 2: one block per (batch, range). Points staged in LDS; top-9-min
// insertion per cell via atomicMin cascade on key = (index<<9)|bucket_pos
// (primary order = original index, unique -> deterministic output regardless
// of bucket arrangement; low bits = free pointer into the staged LDS copy).
// 17 KB LDS -> 8 blocks/CU = 32 waves/CU feeding the 302 MB output stream.
__global__ __launch_bounds__(256) void group_kernel(const unsigned* __restrict__ cnt,
                                                    const float4* __restrict__ bktP,
                                                    const unsigned* __restrict__ bktI,
                                                    float4* __restrict__ out) {
    __shared__ unsigned slots[CR * DEPTH];   // 2304 u32 = 9 KB
    __shared__ float4   staged[CAP];         // 8 KB
    int r = blockIdx.x;
    int b = blockIdx.y;
    int blk = b * RANGES + r;

    uint4* s4 = (uint4*)slots;
    for (int k = threadIdx.x; k < (CR * DEPTH) / 4; k += 256)
        s4[k] = make_uint4(SENT, SENT, SENT, SENT);
    __syncthreads();

    unsigned n = cnt[blk];
    if (n > CAP) n = CAP;
    size_t base = (size_t)blk << CAPSHIFT;

    for (unsigned t = threadIdx.x; t < n; t += 256) {
        float4 p = bktP[base + t];
        unsigned i = bktI[base + t];
        staged[t] = p;
        int xi = (int)(p.x * (float)SHAPE);
        int yi = (int)(p.y * (float)SHAPE);
        unsigned c = (unsigned)(xi * SHAPE + yi) - ((unsigned)r << CRSHIFT);
        unsigned v = (i << CAPSHIFT) | t;
        unsigned* s = &slots[c * DEPTH];
#pragma unroll
        for (int d = 0; d < DEPTH; ++d) {
            unsigned old = atomicMin(&s[d], v);
            if (old == SENT) break;                   // empty slot claimed
            v = (v > old) ? v : old;                  // displaced max continues
        }
    }
    __syncthreads();

    // emit: thread j -> float4 j of this range's contiguous output span
    float4* ob = out + ((size_t)b * NCELLS + ((size_t)r << CRSHIFT)) * DEPTH;
    for (int j = threadIdx.x; j < CR * DEPTH; j += 256) {
        unsigned key = slots[j];
        f32x4 rv = (f32x4){0.f, 0.f, 0.f, 0.f};
        if (key != SENT) {
            float4 p = staged[key & (CAP - 1)];
            float sx = p.x * (float)SHAPE;
            float sy = p.y * (float)SHAPE;
            rv.x = sx - truncf(sx);
            rv.y = sy - truncf(sy);
            rv.z = p.z;
            rv.w = p.w;
        }
        __builtin_nontemporal_store(rv, (f32x4*)&ob[j]);  // pure streaming output
    }
}

// ---- fallback path (stage indices inside d_out; used only if ws too small
//      or per-batch point count exceeds the 18-bit key budget) ----

__global__ void init_kernel(uint4* __restrict__ A, int nVec4) {
    int tid = blockIdx.x * blockDim.x + threadIdx.x;
    if (tid < nVec4) A[tid] = make_uint4(SENT, SENT, SENT, SENT);
}

__global__ void cascade_kernel(const float4* __restrict__ pts,
                               unsigned* A, int nTotal, int nPerB) {
    int tid = blockIdx.x * blockDim.x + threadIdx.x;
    if (tid >= nTotal) return;
    int b = tid / nPerB;
    int i = tid - b * nPerB;
    float4 p = pts[tid];
    if (p.x == 0.f && p.y == 0.f && p.z == 0.f && p.w == 0.f) return;
    int xi = (int)(p.x * (float)SHAPE), yi = (int)(p.y * (float)SHAPE);
    int cell = xi * SHAPE + yi;
    if ((unsigned)cell >= (unsigned)NCELLS) return;
    unsigned v = (unsigned)i;
    unsigned* base = A + (size_t)(b * NCELLS + cell) * (DEPTH * 4);
#pragma unroll
    for (int s = 0; s < DEPTH; ++s) {
        unsigned old = atomicMin(base + s * 4, v);
        if (old == SENT) break;
        v = (v > old) ? v : old;
    }
}

__global__ void write_kernel(const float4* __restrict__ pts,
                             const unsigned* A, float4* out, int nSlots, int nPerB) {
    int tid = blockIdx.x * blockDim.x + threadIdx.x;
    if (tid >= nSlots) return;
    unsigned idx = A[(size_t)tid * 4];
    float4 r = make_float4(0.f, 0.f, 0.f, 0.f);
    if (idx < (unsigned)nPerB) {
        int b = tid / (NCELLS * DEPTH);
        float4 p = pts[(size_t)b * nPerB + idx];
        float sx = p.x * (float)SHAPE, sy = p.y * (float)SHAPE;
        r.x = sx - truncf(sx); r.y = sy - truncf(sy);
        r.z = p.z; r.w = p.w;
    }
    out[tid] = r;
}

extern "C" void kernel_launch(void* const* d_in, const int* in_sizes, int n_in,
                              void* d_out, int out_size, void* d_ws, size_t ws_size,
                              hipStream_t stream) {
    const float4* pts = (const float4*)d_in[0];

    int total = in_sizes[0];               // 8*200000*4
    int nPerB = total / (NB * 4);          // 200,000

    int nBuckets = NB * RANGES;                                         // 8192
    size_t pBytes    = (size_t)nBuckets * CAP * sizeof(float4);         // 64 MB (16B-aligned first)
    size_t iBytes    = (size_t)nBuckets * CAP * sizeof(unsigned);       // 16 MB
    size_t histBytes = (size_t)nBuckets * NCHUNK * sizeof(unsigned);    // 1 MB
    size_t offsBytes = histBytes;                                       // 1 MB
    size_t cntBytes  = (size_t)nBuckets * sizeof(unsigned);             // 32 KB
    size_t need = pBytes + iBytes + histBytes + offsBytes + cntBytes;

    bool fast = (ws_size >= need) && (nPerB <= (1 << 18));
    if (fast) {
        char* w = (char*)d_ws;
        float4*   bktP = (float4*)w;                  w += pBytes;
        unsigned* bktI = (unsigned*)w;                w += iBytes;
        unsigned* hist = (unsigned*)w;                w += histBytes;
        unsigned* offs = (unsigned*)w;                w += offsBytes;
        unsigned* cnt  = (unsigned*)w;

        int chSz = (nPerB + NCHUNK - 1) / NCHUNK;     // 6250

        dim3 cgrid(NCHUNK, NB);
        hist_kernel<<<cgrid, 512, 0, stream>>>(pts, hist, nPerB, chSz);
        prefix_kernel<<<(nBuckets + 255) / 256, 256, 0, stream>>>(hist, offs, cnt);
        scatter_kernel<<<cgrid, 512, 0, stream>>>(pts, offs, bktP, bktI, nPerB, chSz);

        dim3 ggrid(RANGES, NB);
        group_kernel<<<ggrid, 256, 0, stream>>>(cnt, bktP, bktI, (float4*)d_out);
    } else {
        int nPts   = NB * nPerB;
        int nSlots = NB * NCELLS * DEPTH;
        unsigned* A = (unsigned*)d_out;
        int initVec4 = out_size / 4;
        init_kernel<<<(initVec4 + 255) / 256, 256, 0, stream>>>((uint4*)A, initVec4);
        cascade_kernel<<<(nPts + 255) / 256, 256, 0, stream>>>(pts, A, nPts, nPerB);
        write_kernel<<<(nSlots + 255) / 256, 256, 0, stream>>>(
            pts, A, (float4*)d_out, nSlots, nPerB);
    }
}

// Round 8
// 87.344 us; speedup vs baseline: 1.2888x; 1.2888x over previous
//
#include <hip/hip_runtime.h>
#include <stdint.h>

#define SHAPE    512
#define DEPTH    9
#define NCELLS   (SHAPE * SHAPE)
#define NB       8                 // batches
#define RANGES   512               // cell ranges per batch
#define CR       (NCELLS / RANGES) // 512 cells per range
#define CRSHIFT  9
#define CAP      1024              // bucket capacity (mean 391, ~30 sigma headroom)
#define CAPSHIFT 10
#define NCHUNK   64                // point chunks per batch
#define SENT     0xFFFFFFFFu

typedef float f32x4 __attribute__((ext_vector_type(4)));

// ---- fast path: single-pass privatized binning + LDS cascade group ----

__global__ void zero_heads(unsigned* __restrict__ h, int n) {
    int t = blockIdx.x * blockDim.x + threadIdx.x;
    if (t < n) h[t] = 0u;
}

// One dispatch replaces hist+prefix+scatter: per-block LDS histogram over the
// 512 ranges, ONE global atomicAdd per (block,range) reserving a dense bucket
// segment, then direct scatter of packed keys (index<<9 | cell_local, 4 B)
// through LDS cursors. Points re-read from L1/L2 (50 KB chunk). Bucket order
// is arbitrary — group's cascade result depends only on the key multiset.
__global__ __launch_bounds__(512) void bin_kernel(const float4* __restrict__ pts,
                                                  unsigned* __restrict__ headcnt,
                                                  unsigned* __restrict__ bktE,
                                                  int nPerB, int chSz) {
    __shared__ unsigned h[RANGES];
    int c = blockIdx.x, b = blockIdx.y;
    for (int r = threadIdx.x; r < RANGES; r += 512) h[r] = 0u;
    __syncthreads();

    int i0 = c * chSz;
    int i1 = i0 + chSz; if (i1 > nPerB) i1 = nPerB;
    const float4* pb = pts + (size_t)b * nPerB;

    for (int i = i0 + threadIdx.x; i < i1; i += 512) {
        float4 p = pb[i];
        if (p.x == 0.f && p.y == 0.f && p.z == 0.f && p.w == 0.f) continue;
        int xi = (int)(p.x * (float)SHAPE);   // trunc == reference astype(int32)
        int yi = (int)(p.y * (float)SHAPE);
        unsigned cell = (unsigned)(xi * SHAPE + yi);
        if (cell >= (unsigned)NCELLS) continue;
        atomicAdd(&h[cell >> CRSHIFT], 1u);
    }
    __syncthreads();

    for (int r = threadIdx.x; r < RANGES; r += 512) {
        unsigned n = h[r];
        unsigned bucket = (unsigned)(b * RANGES + r);
        unsigned base = n ? atomicAdd(&headcnt[bucket], n) : 0u;
        h[r] = (bucket << CAPSHIFT) + base;            // absolute write cursor
    }
    __syncthreads();

    for (int i = i0 + threadIdx.x; i < i1; i += 512) {
        float4 p = pb[i];
        if (p.x == 0.f && p.y == 0.f && p.z == 0.f && p.w == 0.f) continue;
        int xi = (int)(p.x * (float)SHAPE);
        int yi = (int)(p.y * (float)SHAPE);
        unsigned cell = (unsigned)(xi * SHAPE + yi);
        if (cell >= (unsigned)NCELLS) continue;
        unsigned r = cell >> CRSHIFT;
        unsigned pos = atomicAdd(&h[r], 1u);
        unsigned bucket = (unsigned)(b * RANGES) + r;
        if (pos < ((bucket + 1u) << CAPSHIFT))         // bucket overflow dropped
            bktE[pos] = ((unsigned)i << CRSHIFT) | (cell & (CR - 1));
    }
}

// One block per (batch, range). Top-9-min insertion per cell via LDS atomicMin
// cascade on the packed key: same cell => same low bits, so key order == index
// order (unique) -> slot d ends holding the (d+1)-th earliest point, output is
// deterministic across replays. Emit: LDS read -> (rare, ~8%) L3 gather ->
// coalesced nontemporal float4 store. 18 KB LDS -> 8 blocks/CU = 32 waves/CU.
__global__ __launch_bounds__(256) void group_kernel(const unsigned* __restrict__ headcnt,
                                                    const unsigned* __restrict__ bktE,
                                                    const float4* __restrict__ pts,
                                                    float4* __restrict__ out,
                                                    int nPerB) {
    __shared__ unsigned slots[CR * DEPTH];   // 4608 u32 = 18 KB
    int r = blockIdx.x;
    int b = blockIdx.y;
    int blk = b * RANGES + r;

    uint4* s4 = (uint4*)slots;
    for (int k = threadIdx.x; k < (CR * DEPTH) / 4; k += 256)
        s4[k] = make_uint4(SENT, SENT, SENT, SENT);
    __syncthreads();

    unsigned n = headcnt[blk];
    if (n > CAP) n = CAP;
    size_t base = (size_t)blk << CAPSHIFT;

    for (unsigned t = threadIdx.x; t < n; t += 256) {
        unsigned v = bktE[base + t];
        unsigned* s = &slots[(v & (CR - 1)) * DEPTH];
#pragma unroll
        for (int d = 0; d < DEPTH; ++d) {
            unsigned old = atomicMin(&s[d], v);
            if (old == SENT) break;                   // empty slot claimed
            v = (v > old) ? v : old;                  // displaced max continues
        }
    }
    __syncthreads();

    const float4* pb = pts + (size_t)b * nPerB;
    float4* ob = out + ((size_t)b * NCELLS + ((size_t)r << CRSHIFT)) * DEPTH;
    for (int j = threadIdx.x; j < CR * DEPTH; j += 256) {
        unsigned key = slots[j];
        f32x4 rv = (f32x4){0.f, 0.f, 0.f, 0.f};
        if (key != SENT) {
            float4 p = pb[key >> CRSHIFT];            // L2/L3-resident gather
            float sx = p.x * (float)SHAPE;
            float sy = p.y * (float)SHAPE;
            rv.x = sx - truncf(sx);
            rv.y = sy - truncf(sy);
            rv.z = p.z;
            rv.w = p.w;
        }
        __builtin_nontemporal_store(rv, (f32x4*)&ob[j]);  // pure streaming output
    }
}

// ---- fallback path (stage indices inside d_out; used only if ws too small
//      or per-batch point count exceeds the 18-bit key budget) ----

__global__ void init_kernel(uint4* __restrict__ A, int nVec4) {
    int tid = blockIdx.x * blockDim.x + threadIdx.x;
    if (tid < nVec4) A[tid] = make_uint4(SENT, SENT, SENT, SENT);
}

__global__ void cascade_kernel(const float4* __restrict__ pts,
                               unsigned* A, int nTotal, int nPerB) {
    int tid = blockIdx.x * blockDim.x + threadIdx.x;
    if (tid >= nTotal) return;
    int b = tid / nPerB;
    int i = tid - b * nPerB;
    float4 p = pts[tid];
    if (p.x == 0.f && p.y == 0.f && p.z == 0.f && p.w == 0.f) return;
    int xi = (int)(p.x * (float)SHAPE), yi = (int)(p.y * (float)SHAPE);
    int cell = xi * SHAPE + yi;
    if ((unsigned)cell >= (unsigned)NCELLS) return;
    unsigned v = (unsigned)i;
    unsigned* base = A + (size_t)(b * NCELLS + cell) * (DEPTH * 4);
#pragma unroll
    for (int s = 0; s < DEPTH; ++s) {
        unsigned old = atomicMin(base + s * 4, v);
        if (old == SENT) break;
        v = (v > old) ? v : old;
    }
}

__global__ void write_kernel(const float4* __restrict__ pts,
                             const unsigned* A, float4* out, int nSlots, int nPerB) {
    int tid = blockIdx.x * blockDim.x + threadIdx.x;
    if (tid >= nSlots) return;
    unsigned idx = A[(size_t)tid * 4];
    float4 r = make_float4(0.f, 0.f, 0.f, 0.f);
    if (idx < (unsigned)nPerB) {
        int b = tid / (NCELLS * DEPTH);
        float4 p = pts[(size_t)b * nPerB + idx];
        float sx = p.x * (float)SHAPE, sy = p.y * (float)SHAPE;
        r.x = sx - truncf(sx); r.y = sy - truncf(sy);
        r.z = p.z; r.w = p.w;
    }
    out[tid] = r;
}

extern "C" void kernel_launch(void* const* d_in, const int* in_sizes, int n_in,
                              void* d_out, int out_size, void* d_ws, size_t ws_size,
                              hipStream_t stream) {
    const float4* pts = (const float4*)d_in[0];

    int total = in_sizes[0];               // 8*200000*4
    int nPerB = total / (NB * 4);          // 200,000

    int nBuckets = NB * RANGES;                                       // 4096
    size_t eBytes = (size_t)nBuckets * CAP * sizeof(unsigned);        // 16 MB
    size_t hBytes = (size_t)nBuckets * sizeof(unsigned);              // 16 KB
    size_t need = eBytes + hBytes;

    bool fast = (ws_size >= need) && (nPerB <= (1 << 18));
    if (fast) {
        unsigned* bktE    = (unsigned*)d_ws;
        unsigned* headcnt = (unsigned*)((char*)d_ws + eBytes);

        int chSz = (nPerB + NCHUNK - 1) / NCHUNK;     // 3125

        zero_heads<<<(nBuckets + 255) / 256, 256, 0, stream>>>(headcnt, nBuckets);

        dim3 bgrid(NCHUNK, NB);
        bin_kernel<<<bgrid, 512, 0, stream>>>(pts, headcnt, bktE, nPerB, chSz);

        dim3 ggrid(RANGES, NB);
        group_kernel<<<ggrid, 256, 0, stream>>>(headcnt, bktE, pts, (float4*)d_out, nPerB);
    } else {
        int nPts   = NB * nPerB;
        int nSlots = NB * NCELLS * DEPTH;
        unsigned* A = (unsigned*)d_out;
        int initVec4 = out_size / 4;
        init_kernel<<<(initVec4 + 255) / 256, 256, 0, stream>>>((uint4*)A, initVec4);
        cascade_kernel<<<(nPts + 255) / 256, 256, 0, stream>>>(pts, A, nPts, nPerB);
        write_kernel<<<(nSlots + 255) / 256, 256, 0, stream>>>(
            pts, A, (float4*)d_out, nSlots, nPerB);
    }
}